// Round 2
// baseline (978.832 us; speedup 1.0000x reference)
//
#include <hip/hip_runtime.h>

// ---------------------------------------------------------------------------
// Two stacked SwinV2 shifted-window attentions, MI355X/gfx950.
// Pipeline: t_in (NCHW->NHWC, float4 both sides) -> [k_swin fused] x2 -> t_out.
// k_swin v2: wave w owns whole q/k section (w0=q0,w1=q1,w2=k0,w3=k1) + 1/4 of V
//   -> norms in-register via shfl (norm phase + 1 barrier/iter deleted),
//   V written transposed (packed b64) straight from the GEMM epilogue,
//   cpb bias table staged in LDS as [head][rel], rel/mask precomputed in regs.
// ---------------------------------------------------------------------------

typedef short bf16x8 __attribute__((ext_vector_type(8)));
typedef float f32x4 __attribute__((ext_vector_type(4)));

__device__ __forceinline__ unsigned short f2bf(float f) {
    union { float f; unsigned int u; } v; v.f = f;
    return (unsigned short)((v.u + 0x7fffu + ((v.u >> 16) & 1u)) >> 16);
}
__device__ __forceinline__ float bf2f(unsigned short b) {
    union { unsigned int u; float f; } v; v.u = ((unsigned int)b) << 16;
    return v.f;
}
__device__ __forceinline__ f32x4 mfma_bf16(bf16x8 a, bf16x8 b, f32x4 c) {
    return __builtin_amdgcn_mfma_f32_16x16x32_bf16(a, b, c, 0, 0, 0);
}

// region id for the swin shifted mask (pH=pW=64, ws=8, shift=4).
__device__ __forceinline__ int region_of(int wh, int ww, int t) {
    int th = t >> 3, tw = t & 7;
    int rh = (wh == 7) ? ((th < 4) ? 1 : 2) : 0;
    int rw = (ww == 7) ? ((tw < 4) ? 1 : 2) : 0;
    return rh * 3 + rw;
}

// ---------------------------------------------------------------------------
// setup: blocks 0..511 convert weights f32->bf16; blocks 512/513 compute the
// continuous-relative-position-bias tables (already through 16*sigmoid).
// ---------------------------------------------------------------------------
__global__ __launch_bounds__(256) void k_setup(
    const float* __restrict__ qkvw1, const float* __restrict__ projw1,
    const float* __restrict__ qkvw2, const float* __restrict__ projw2,
    const float* __restrict__ w1a, const float* __restrict__ b1a, const float* __restrict__ w2a,
    const float* __restrict__ w1b, const float* __restrict__ b1b, const float* __restrict__ w2b,
    unsigned short* __restrict__ qw1, unsigned short* __restrict__ pw1,
    unsigned short* __restrict__ qw2, unsigned short* __restrict__ pw2,
    float* __restrict__ bt1, float* __restrict__ bt2)
{
    int b = blockIdx.x, t = threadIdx.x;
    if (b < 512) {
        int idx = b * 256 + t;
        #pragma unroll
        for (int r = 0; r < 4; r++) {
            int i = idx + r * 131072;
            if (i < 196608)        qw1[i]          = f2bf(qkvw1[i]);
            else if (i < 262144)   pw1[i - 196608] = f2bf(projw1[i - 196608]);
            else if (i < 458752)   qw2[i - 262144] = f2bf(qkvw2[i - 262144]);
            else                   pw2[i - 458752] = f2bf(projw2[i - 458752]);
        }
    } else {
        int a = b - 512;
        const float* w1 = a ? w1b : w1a;
        const float* b1 = a ? b1b : b1a;
        const float* w2 = a ? w2b : w2a;
        float* out = a ? bt2 : bt1;
        int k = t;
        if (k >= 225) return;
        int ih = k / 15, iw = k % 15;
        float v0 = (float)(ih - 7) / 7.0f * 8.0f;
        float v1 = (float)(iw - 7) / 7.0f * 8.0f;
        float t0 = (v0 >= 0.f ? 1.f : -1.f) * log2f(fabsf(v0) + 1.f) / 3.0f;
        float t1 = (v1 >= 0.f ? 1.f : -1.f) * log2f(fabsf(v1) + 1.f) / 3.0f;
        float acc[8] = {0.f, 0.f, 0.f, 0.f, 0.f, 0.f, 0.f, 0.f};
        for (int c = 0; c < 512; c++) {
            float hc = t0 * w1[2 * c] + t1 * w1[2 * c + 1] + b1[c];
            hc = fmaxf(hc, 0.f);
            #pragma unroll
            for (int h = 0; h < 8; h++) acc[h] += hc * w2[h * 512 + c];
        }
        #pragma unroll
        for (int h = 0; h < 8; h++) out[k * 8 + h] = 16.f / (1.f + expf(-acc[h]));
    }
}

// ---------------------------------------------------------------------------
// transposes: src [32][256][4096] <-> NHWC [32][4096][256]
// 128(hw) x 32(c) tiles, float4 global loads AND stores. LDS tile [32][132]
// (132 floats = 528 B row stride: 16B-aligned for b128, bank spread ok).
// ---------------------------------------------------------------------------
__global__ __launch_bounds__(256) void t_in(const float* __restrict__ src, float* __restrict__ dst) {
    __shared__ float tile[32][132];
    int img = blockIdx.z, hw0 = blockIdx.x * 128, c0 = blockIdx.y * 32;
    int tid = threadIdx.x;
    #pragma unroll
    for (int k = 0; k < 4; k++) {
        int cl = (tid >> 5) + k * 8;
        int hw4 = (tid & 31) * 4;
        float4 v = *(const float4*)(src + ((size_t)img * 256 + c0 + cl) * 4096 + hw0 + hw4);
        *(float4*)&tile[cl][hw4] = v;
    }
    __syncthreads();
    #pragma unroll
    for (int j = 0; j < 4; j++) {
        int hwl = (tid >> 3) + j * 32;
        int c4 = (tid & 7) * 4;
        float4 o;
        o.x = tile[c4 + 0][hwl]; o.y = tile[c4 + 1][hwl];
        o.z = tile[c4 + 2][hwl]; o.w = tile[c4 + 3][hwl];
        *(float4*)(dst + ((size_t)img * 4096 + hw0 + hwl) * 256 + c0 + c4) = o;
    }
}

__global__ __launch_bounds__(256) void t_out(const float* __restrict__ src, float* __restrict__ dst) {
    __shared__ float tile[32][132];
    int img = blockIdx.z, hw0 = blockIdx.x * 128, c0 = blockIdx.y * 32;
    int tid = threadIdx.x;
    #pragma unroll
    for (int j = 0; j < 4; j++) {
        int hwl = (tid >> 3) + j * 32;
        int c4 = (tid & 7) * 4;
        float4 v = *(const float4*)(src + ((size_t)img * 4096 + hw0 + hwl) * 256 + c0 + c4);
        tile[c4 + 0][hwl] = v.x; tile[c4 + 1][hwl] = v.y;
        tile[c4 + 2][hwl] = v.z; tile[c4 + 3][hwl] = v.w;
    }
    __syncthreads();
    #pragma unroll
    for (int k = 0; k < 4; k++) {
        int cl = (tid >> 5) + k * 8;
        int hw4 = (tid & 31) * 4;
        float4 o = *(const float4*)&tile[cl][hw4];
        *(float4*)(dst + ((size_t)img * 256 + c0 + cl) * 4096 + hw0 + hw4) = o;
    }
}

// ---------------------------------------------------------------------------
// k_swin: one block per window (2048 blocks, 256 thr = 4 waves).
// Phase A: 4 head-pair iterations, 2 barriers each:
//   QKV GEMM (wave w: q/k section w + V quarter w) -> epilogue writes sQKV
//   (q0|q1|k0|k1) + sVt (transposed, packed) + in-register norms -> sInv
//   -> barrier -> per head: S=Qn Kn^T*scale + bias(LDS) (+mask regs)
//   -> softmax -> PV -> AO (global, block-local) -> barrier.
// Phase B: re-stage own AO tile (L2-hot), proj GEMM + bias + residual scatter.
// ---------------------------------------------------------------------------
__global__ __launch_bounds__(256, 2) void k_swin(
    const float* __restrict__ Xin,           // NHWC f32 [32][64][64][256] (also residual)
    const unsigned short* __restrict__ Wq,   // qkv_w bf16 [768][256]
    const float* __restrict__ bq,            // qkv_b f32 [768]
    const float* __restrict__ lsc,           // logit_scale [8]
    const float* __restrict__ btab,          // 16*sigmoid(bias) f32 [225][8]
    const unsigned short* __restrict__ Wp,   // proj_w bf16 [256][256]
    const float* __restrict__ bp,            // proj_b [256]
    unsigned short* __restrict__ AO,         // attn_out bf16 [2048][64][256] (scratch)
    float* __restrict__ Xout,                // output NHWC f32
    int shift, int masked)
{
    __shared__ __align__(16) unsigned short sX[64 * 264];    // X window bf16; reused for O in phase B
    __shared__ __align__(16) unsigned short sQKV[64 * 136];  // q0|q1|k0|k1 (32 chans each)
    __shared__ __align__(16) unsigned short sP[64 * 72];     // softmax probs bf16
    __shared__ __align__(16) unsigned short sVt[64 * 72];    // V transposed [dim][token]
    __shared__ float sInv[4 * 64];                           // 1/norm: q0,q1,k0,k1
    __shared__ float sBias[8 * 225];                         // bias table [head][rel]

    const int tid = threadIdx.x;
    const int wv = tid >> 6, lane = tid & 63, quad = lane >> 4, nn = lane & 15;
    const int win = blockIdx.x;
    const int bt = win >> 6, wh = (win >> 3) & 7, ww = win & 7;
    const f32x4 zero4 = {0.f, 0.f, 0.f, 0.f};

    // ---- stage bias table (transposed for bank spread on rel-gathers) ----
    for (int i = tid; i < 1800; i += 256) {
        int h = i / 225, rel = i - h * 225;
        sBias[i] = btab[rel * 8 + h];
    }

    // ---- stage X window (shift roll folded into the gather) ----
    {
        int tok = tid >> 2, part = tid & 3;
        int h = (wh * 8 + (tok >> 3) + shift) & 63;
        int w = (ww * 8 + (tok & 7) + shift) & 63;
        const float* srcp = Xin + ((size_t)(bt * 4096 + h * 64 + w)) * 256 + part * 64;
        unsigned short* dstp = sX + tok * 264 + part * 64;
        #pragma unroll
        for (int c = 0; c < 64; c += 8) {
            float4 v0 = *(const float4*)(srcp + c);
            float4 v1 = *(const float4*)(srcp + c + 4);
            uint4 o;
            o.x = (unsigned int)f2bf(v0.x) | ((unsigned int)f2bf(v0.y) << 16);
            o.y = (unsigned int)f2bf(v0.z) | ((unsigned int)f2bf(v0.w) << 16);
            o.z = (unsigned int)f2bf(v1.x) | ((unsigned int)f2bf(v1.y) << 16);
            o.w = (unsigned int)f2bf(v1.z) | ((unsigned int)f2bf(v1.w) << 16);
            *(uint4*)(dstp + c) = o;
        }
    }
    __syncthreads();

    // ---- per-thread constants: rel-bias offsets + mask addend (registers) ----
    int reloff[4][4];
    float madd[4][4];
    #pragma unroll
    for (int ct = 0; ct < 4; ct++) {
        int j = ct * 16 + nn;
        int rj = region_of(wh, ww, j);
        #pragma unroll
        for (int r = 0; r < 4; r++) {
            int i = wv * 16 + quad * 4 + r;
            reloff[ct][r] = ((i >> 3) - (j >> 3) + 7) * 15 + ((i & 7) - (j & 7) + 7);
            madd[ct][r] = (masked && (region_of(wh, ww, i) != rj)) ? -100.f : 0.f;
        }
    }

    const int kind = wv >> 1;        // 0 = q (waves 0,1), 1 = k (waves 2,3)
    const int hsel = wv & 1;         // head-within-pair for the q/k section
    const int vc = wv * 16 + nn;     // this thread's V output dim (0..63)

    // ======================= Phase A: attention =======================
    for (int p = 0; p < 4; p++) {
        // ===== QKV GEMM: wave w computes q/k section w (32 chans) + V quarter =====
        f32x4 acc[4][3];
        #pragma unroll
        for (int rt = 0; rt < 4; rt++)
            #pragma unroll
            for (int c = 0; c < 3; c++) acc[rt][c] = zero4;

        int wrow[3];
        wrow[0] = kind * 256 + (2 * p + hsel) * 32 + nn;        // q/k chan, low 16
        wrow[1] = wrow[0] + 16;                                  // q/k chan, high 16
        wrow[2] = 512 + (2 * p + (vc >> 5)) * 32 + (vc & 31);    // v chan

        #pragma unroll
        for (int ks = 0; ks < 8; ks++) {
            bf16x8 a[4], b[3];
            #pragma unroll
            for (int rt = 0; rt < 4; rt++)
                a[rt] = *(const bf16x8*)(sX + (rt * 16 + nn) * 264 + ks * 32 + quad * 8);
            #pragma unroll
            for (int c = 0; c < 3; c++)
                b[c] = *(const bf16x8*)(Wq + (size_t)wrow[c] * 256 + ks * 32 + quad * 8);
            #pragma unroll
            for (int rt = 0; rt < 4; rt++)
                #pragma unroll
                for (int c = 0; c < 3; c++)
                    acc[rt][c] = mfma_bf16(a[rt], b[c], acc[rt][c]);
        }

        // ===== epilogue: write q/k to sQKV + in-register sum-of-squares =====
        float ssq[4][4];
        #pragma unroll
        for (int rt = 0; rt < 4; rt++)
            #pragma unroll
            for (int r = 0; r < 4; r++) ssq[rt][r] = 0.f;

        #pragma unroll
        for (int ctl = 0; ctl < 2; ctl++) {
            float bias = kind ? 0.f : bq[wrow[ctl]];   // v2 zeroes key bias
            int col = wv * 32 + ctl * 16 + nn;
            #pragma unroll
            for (int rt = 0; rt < 4; rt++)
                #pragma unroll
                for (int r = 0; r < 4; r++) {
                    float val = acc[rt][ctl][r] + bias;
                    ssq[rt][r] += val * val;
                    sQKV[(rt * 16 + quad * 4 + r) * 136 + col] = f2bf(val);
                }
        }
        // V: packed transposed write (4 consecutive tokens per b64)
        {
            float bv = bq[wrow[2]];
            #pragma unroll
            for (int rt = 0; rt < 4; rt++) {
                ushort4 pk;
                pk.x = f2bf(acc[rt][2][0] + bv);
                pk.y = f2bf(acc[rt][2][1] + bv);
                pk.z = f2bf(acc[rt][2][2] + bv);
                pk.w = f2bf(acc[rt][2][3] + bv);
                *(ushort4*)(sVt + vc * 72 + rt * 16 + quad * 4) = pk;
            }
        }
        // norms: reduce 32 chans (2 ctl x 16 nn lanes) within the quad
        #pragma unroll
        for (int rt = 0; rt < 4; rt++)
            #pragma unroll
            for (int r = 0; r < 4; r++) {
                float s = ssq[rt][r];
                s += __shfl_xor(s, 1);
                s += __shfl_xor(s, 2);
                s += __shfl_xor(s, 4);
                s += __shfl_xor(s, 8);
                if (nn == 0)
                    sInv[wv * 64 + rt * 16 + quad * 4 + r] = 1.f / fmaxf(sqrtf(s), 1e-12f);
            }
        __syncthreads();

        #pragma unroll
        for (int hh = 0; hh < 2; hh++) {
            const int head = 2 * p + hh;
            const float scale = __expf(fminf(lsc[head], 4.605170185988092f)); // ln(100)
            const float* bh = sBias + head * 225;

            // ----- S = Q K^T (wave wv owns rows wv*16..wv*16+15) -----
            bf16x8 aq = *(const bf16x8*)(sQKV + (wv * 16 + nn) * 136 + hh * 32 + quad * 8);
            f32x4 S[4];
            #pragma unroll
            for (int ct = 0; ct < 4; ct++) {
                bf16x8 bk = *(const bf16x8*)(sQKV + (ct * 16 + nn) * 136 + 64 + hh * 32 + quad * 8);
                S[ct] = mfma_bf16(aq, bk, zero4);
            }

            const int i_base = wv * 16 + quad * 4;
            float iq[4];
            #pragma unroll
            for (int r = 0; r < 4; r++) iq[r] = sInv[hh * 64 + i_base + r];

            float rowm[4] = {-3.0e38f, -3.0e38f, -3.0e38f, -3.0e38f};
            #pragma unroll
            for (int ct = 0; ct < 4; ct++) {
                int j = ct * 16 + nn;
                float ivk = sInv[(2 + hh) * 64 + j];
                #pragma unroll
                for (int r = 0; r < 4; r++) {
                    float v = S[ct][r] * iq[r] * ivk * scale + bh[reloff[ct][r]] + madd[ct][r];
                    S[ct][r] = v;
                    rowm[r] = fmaxf(rowm[r], v);
                }
            }
            #pragma unroll
            for (int r = 0; r < 4; r++) {
                float m = rowm[r];
                m = fmaxf(m, __shfl_xor(m, 1));
                m = fmaxf(m, __shfl_xor(m, 2));
                m = fmaxf(m, __shfl_xor(m, 4));
                m = fmaxf(m, __shfl_xor(m, 8));
                rowm[r] = m;
            }
            float rsum[4] = {0.f, 0.f, 0.f, 0.f};
            #pragma unroll
            for (int ct = 0; ct < 4; ct++)
                #pragma unroll
                for (int r = 0; r < 4; r++) {
                    float e = __expf(S[ct][r] - rowm[r]);
                    S[ct][r] = e;
                    rsum[r] += e;
                }
            #pragma unroll
            for (int r = 0; r < 4; r++) {
                float s = rsum[r];
                s += __shfl_xor(s, 1);
                s += __shfl_xor(s, 2);
                s += __shfl_xor(s, 4);
                s += __shfl_xor(s, 8);
                rsum[r] = 1.f / s;
            }
            // write P (wave-private rows -> no barrier needed before PV)
            #pragma unroll
            for (int ct = 0; ct < 4; ct++)
                #pragma unroll
                for (int r = 0; r < 4; r++)
                    sP[(i_base + r) * 72 + ct * 16 + nn] = f2bf(S[ct][r] * rsum[r]);

            // ----- O = P V  (K=64 -> 2 ksteps; 2 col tiles of 16 dims) -----
            bf16x8 ap0 = *(const bf16x8*)(sP + (wv * 16 + nn) * 72 + quad * 8);
            bf16x8 ap1 = *(const bf16x8*)(sP + (wv * 16 + nn) * 72 + 32 + quad * 8);
            #pragma unroll
            for (int ct2 = 0; ct2 < 2; ct2++) {
                bf16x8 bv0 = *(const bf16x8*)(sVt + (hh * 32 + ct2 * 16 + nn) * 72 + quad * 8);
                bf16x8 bv1 = *(const bf16x8*)(sVt + (hh * 32 + ct2 * 16 + nn) * 72 + 32 + quad * 8);
                f32x4 O = mfma_bf16(ap0, bv0, zero4);
                O = mfma_bf16(ap1, bv1, O);
                #pragma unroll
                for (int r = 0; r < 4; r++) {
                    int tokr = i_base + r;
                    AO[((size_t)win * 64 + tokr) * 256 + head * 32 + ct2 * 16 + nn] = f2bf(O[r]);
                }
            }
        }
        __syncthreads();  // protect sQKV/sVt/sInv before next pair; drains AO stores
    }

    // ======================= Phase B: projection =======================
    {
        int tok = tid >> 2, part = tid & 3;
        const unsigned short* srcp = AO + ((size_t)win * 64 + tok) * 256 + part * 64;
        unsigned short* dstp = sX + tok * 264 + part * 64;
        #pragma unroll
        for (int c = 0; c < 64; c += 8)
            *(uint4*)(dstp + c) = *(const uint4*)(srcp + c);
    }
    __syncthreads();

    f32x4 pacc[4][4];
    #pragma unroll
    for (int rt = 0; rt < 4; rt++)
        #pragma unroll
        for (int c = 0; c < 4; c++) pacc[rt][c] = zero4;

    int prow[4];
    #pragma unroll
    for (int c = 0; c < 4; c++) prow[c] = (wv * 4 + c) * 16 + nn;  // output channel

    #pragma unroll
    for (int ks = 0; ks < 8; ks++) {
        bf16x8 a[4], b[4];
        #pragma unroll
        for (int rt = 0; rt < 4; rt++)
            a[rt] = *(const bf16x8*)(sX + (rt * 16 + nn) * 264 + ks * 32 + quad * 8);
        #pragma unroll
        for (int c = 0; c < 4; c++)
            b[c] = *(const bf16x8*)(Wp + (size_t)prow[c] * 256 + ks * 32 + quad * 8);
        #pragma unroll
        for (int rt = 0; rt < 4; rt++)
            #pragma unroll
            for (int c = 0; c < 4; c++)
                pacc[rt][c] = mfma_bf16(a[rt], b[c], pacc[rt][c]);
    }

    #pragma unroll
    for (int c = 0; c < 4; c++) {
        int chan = prow[c];
        float bias = bp[chan];
        #pragma unroll
        for (int rt = 0; rt < 4; rt++)
            #pragma unroll
            for (int r = 0; r < 4; r++) {
                int tok = rt * 16 + quad * 4 + r;
                int h = (wh * 8 + (tok >> 3) + shift) & 63;
                int w = (ww * 8 + (tok & 7) + shift) & 63;
                size_t idx = ((size_t)(bt * 4096 + h * 64 + w)) * 256 + chan;
                Xout[idx] = pacc[rt][c][r] + bias + Xin[idx];
            }
    }
}

// ---------------------------------------------------------------------------
extern "C" void kernel_launch(void* const* d_in, const int* in_sizes, int n_in,
                              void* d_out, int out_size, void* d_ws, size_t ws_size,
                              hipStream_t stream) {
    (void)in_sizes; (void)n_in; (void)out_size; (void)ws_size;

    const float* src        = (const float*)d_in[0];
    const float* a1_qkv_w   = (const float*)d_in[1];
    const float* a1_qkv_b   = (const float*)d_in[2];
    const float* a1_proj_w  = (const float*)d_in[3];
    const float* a1_proj_b  = (const float*)d_in[4];
    const float* a1_ls      = (const float*)d_in[5];
    const float* a1_w1      = (const float*)d_in[6];
    const float* a1_b1      = (const float*)d_in[7];
    const float* a1_w2      = (const float*)d_in[8];
    const float* a2_qkv_w   = (const float*)d_in[9];
    const float* a2_qkv_b   = (const float*)d_in[10];
    const float* a2_proj_w  = (const float*)d_in[11];
    const float* a2_proj_b  = (const float*)d_in[12];
    const float* a2_ls      = (const float*)d_in[13];
    const float* a2_w1      = (const float*)d_in[14];
    const float* a2_b1      = (const float*)d_in[15];
    const float* a2_w2      = (const float*)d_in[16];

    char* ws = (char*)d_ws;
    const size_t SZ_X = 134217728;  // 32*4096*256*4
    float* X0 = (float*)(ws);
    float* X1 = (float*)(ws + SZ_X);
    unsigned short* AO  = (unsigned short*)(ws + 2 * SZ_X);          // 67108864 B
    unsigned short* qw1 = (unsigned short*)(ws + 2 * SZ_X + 67108864);
    unsigned short* qw2 = qw1 + 196608;
    unsigned short* pw1 = qw2 + 196608;
    unsigned short* pw2 = pw1 + 65536;
    float* bt1 = (float*)(pw2 + 65536);
    float* bt2 = bt1 + 1800;

    k_setup<<<514, 256, 0, stream>>>(a1_qkv_w, a1_proj_w, a2_qkv_w, a2_proj_w,
                                     a1_w1, a1_b1, a1_w2, a2_w1, a2_b1, a2_w2,
                                     qw1, pw1, qw2, pw2, bt1, bt2);
    t_in<<<dim3(32, 8, 32), 256, 0, stream>>>(src, X0);

    // pass 1: no shift, no mask (attn+proj fused, per-window)
    k_swin<<<2048, 256, 0, stream>>>(X0, qw1, a1_qkv_b, a1_ls, bt1, pw1, a1_proj_b, AO, X1, 0, 0);
    // pass 2: shift 4, masked
    k_swin<<<2048, 256, 0, stream>>>(X1, qw2, a2_qkv_b, a2_ls, bt2, pw2, a2_proj_b, AO, X0, 4, 1);

    t_out<<<dim3(32, 8, 32), 256, 0, stream>>>(X0, (float*)d_out);
}